// Round 11
// baseline (502.728 us; speedup 1.0000x reference)
//
#include <hip/hip_runtime.h>
#include <hip/hip_bf16.h>
#include <cstdio>

typedef __attribute__((ext_vector_type(8))) short short8;
typedef __attribute__((ext_vector_type(4))) short short4v;
typedef __attribute__((ext_vector_type(4))) float f32x4;

template <int H> struct VecT;
template <> struct VecT<8> { using T = short8; };
template <> struct VecT<4> { using T = short4v; };

// ---------- bf16 helpers ----------
__device__ __forceinline__ float bfu2f(unsigned short u) {
    return __uint_as_float(((unsigned)u) << 16);
}
__device__ __forceinline__ unsigned short f2bfu(float f) {   // RNE
    __hip_bfloat16 b = __float2bfloat16(f);
    union { __hip_bfloat16 b; unsigned short u; } cv; cv.b = b;
    return cv.u;
}

// split 8 fp32 -> hi/lo bf16x8, store to LDS
__device__ __forceinline__ void splitStore8(float4 a, float4 b,
                                            unsigned short* dhi, unsigned short* dlo) {
    float v[8] = {a.x, a.y, a.z, a.w, b.x, b.y, b.z, b.w};
    short8 h8, l8;
#pragma unroll
    for (int j = 0; j < 8; j++) {
        unsigned short hh = f2bfu(v[j]);
        h8[j] = (short)hh;
        l8[j] = (short)f2bfu(v[j] - bfu2f(hh));
    }
    *(short8*)dhi = h8;
    *(short8*)dlo = l8;
}

// ---------- graph/model dims ----------
#define N1 80000
#define N2 16000
#define N3 4096
#define E1 256000
#define E2 65536

// ---------- fused prep: all weight splits + int zeroing in one launch ----------
__global__ void prep_kernel(const float* __restrict__ W1s, const float* __restrict__ W1d,
                            unsigned short* __restrict__ w1s_hi, unsigned short* __restrict__ w1s_lo,
                            unsigned short* __restrict__ w1d_hi, unsigned short* __restrict__ w1d_lo,
                            const float* __restrict__ W2s, const float* __restrict__ W2d,
                            unsigned short* __restrict__ w2s_hi, unsigned short* __restrict__ w2s_lo,
                            unsigned short* __restrict__ w2d_hi, unsigned short* __restrict__ w2d_lo,
                            const float* __restrict__ fW, unsigned short* __restrict__ fw_t3,
                            int* __restrict__ zbase, int zn) {
    int i = blockIdx.x * blockDim.x + threadIdx.x;
    const int S0 = 262144, S1 = 262144, S2 = 8192;
    if (i < S0) {
        const float* W = (i < 131072) ? W1s : W1d;
        unsigned short* hi = (i < 131072) ? w1s_hi : w1d_hi;
        unsigned short* lo = (i < 131072) ? w1s_lo : w1d_lo;
        int j = i & 131071;
        int k = j >> 9, n = j & 511;            // K=256, N=512
        float v = W[j];
        unsigned short h = f2bfu(v);
        hi[(size_t)n * 256 + k] = h;
        lo[(size_t)n * 256 + k] = f2bfu(v - bfu2f(h));
    } else if (i < S0 + S1) {
        int ii = i - S0;
        const float* W = (ii < 131072) ? W2s : W2d;
        unsigned short* hi = (ii < 131072) ? w2s_hi : w2d_hi;
        unsigned short* lo = (ii < 131072) ? w2s_lo : w2d_lo;
        int j = ii & 131071;
        int k = j >> 8, n = j & 255;            // K=512, N=256
        float v = W[j];
        unsigned short h = f2bfu(v);
        hi[(size_t)n * 512 + k] = h;
        lo[(size_t)n * 512 + k] = f2bfu(v - bfu2f(h));
    } else if (i < S0 + S1 + S2) {
        int j = i - S0 - S1;
        int k = j >> 6, n = j & 63;             // K=128, N=64
        float v = fW[j];
        unsigned short h = f2bfu(v);
        unsigned short l = f2bfu(v - bfu2f(h));
        size_t base = (size_t)n * 384;
        fw_t3[base + k] = h;
        fw_t3[base + 128 + k] = l;
        fw_t3[base + 256 + k] = h;
    } else {
        int j = i - S0 - S1 - S2;
        if (j < zn) zbase[j] = 0;
    }
}

// ---------- CSR build (both graphs per launch) ----------
__global__ void hist_dual(const int* __restrict__ d1, int* __restrict__ c1,
                          const int* __restrict__ d2, int* __restrict__ c2) {
    int i = blockIdx.x * blockDim.x + threadIdx.x;
    if (i < E1) {
        int d = d1[i];
        if ((unsigned)d < (unsigned)N2) atomicAdd(&c1[d], 1);
    } else if (i < E1 + E2) {
        int d = d2[i - E1];
        if ((unsigned)d < (unsigned)N3) atomicAdd(&c2[d], 1);
    }
}
__global__ __launch_bounds__(1024)
void scan_dual(const int* __restrict__ c1, int* __restrict__ s1, int Nd1,
               const int* __restrict__ c2, int* __restrict__ s2, int Nd2) {
    const int* cnt = (blockIdx.x == 0) ? c1 : c2;
    int* start = (blockIdx.x == 0) ? s1 : s2;
    int Nd = (blockIdx.x == 0) ? Nd1 : Nd2;
    __shared__ int part[1024];
    int t = threadIdx.x;
    int k = (Nd + 1023) >> 10;
    int lo = t * k, hi = min(lo + k, Nd);
    if (lo > Nd) lo = Nd;
    int s = 0;
    for (int i = lo; i < hi; i++) s += cnt[i];
    part[t] = s;
    __syncthreads();
    for (int off = 1; off < 1024; off <<= 1) {
        int v = (t >= off) ? part[t - off] : 0;
        __syncthreads();
        part[t] += v;
        __syncthreads();
    }
    int run = (t > 0) ? part[t - 1] : 0;
    for (int i = lo; i < hi; i++) { start[i] = run; run += cnt[i]; }
    if (t == 1023) start[Nd] = part[1023];
}
__global__ void fill_dual(const int* __restrict__ sa1, const int* __restrict__ da1,
                          const int* __restrict__ st1, int* __restrict__ cu1, int* __restrict__ cs1,
                          const int* __restrict__ sa2, const int* __restrict__ da2,
                          const int* __restrict__ st2, int* __restrict__ cu2, int* __restrict__ cs2) {
    int i = blockIdx.x * blockDim.x + threadIdx.x;
    const int *sa, *da, *st;
    int *cu, *cs;
    int Nd, Ns, e;
    if (i < E1) { sa = sa1; da = da1; st = st1; cu = cu1; cs = cs1; Nd = N2; Ns = N1; e = i; }
    else if (i < E1 + E2) { sa = sa2; da = da2; st = st2; cu = cu2; cs = cs2; Nd = N3; Ns = N2; e = i - E1; }
    else return;
    int d = da[e];
    if ((unsigned)d >= (unsigned)Nd) return;
    int p = atomicAdd(&cu[d], 1);
    int idx = st[d] + p;
    if (idx >= st[d + 1]) return;
    int s = sa[e];
    if ((unsigned)s >= (unsigned)Ns) s = 0;
    cs[idx] = s;
}

// ---------- FUSED MFMA GEMM, 64x256 tile, 2-deep A prefetch pipeline ----------
// A [*,K] fp32 (register prefetch -> hi/lo split -> double-buffered LDS);
// B hi/lo [N][K] bf16 register-direct (L2-resident). K % 64 == 0.
// grid.y in [0,Mb1) -> sub-GEMM 1, else sub-GEMM 2. Fused escore epilogue.
__global__ __launch_bounds__(256, 3)
void gemm_fused(const float* __restrict__ A,
                const unsigned short* __restrict__ Bhi1, const unsigned short* __restrict__ Blo1,
                unsigned short* __restrict__ C1, const float* __restrict__ att1,
                float* __restrict__ es1,
                const unsigned short* __restrict__ Bhi2, const unsigned short* __restrict__ Blo2,
                unsigned short* __restrict__ C2, const float* __restrict__ att2,
                float* __restrict__ es2,
                int Mb1, int N, int K, int H) {
    __shared__ unsigned short As[2][2][64][40];   // [buf][hi/lo][row][k]
    const unsigned short *Bhi, *Blo;
    unsigned short* C;
    const float* att;
    float* es_out;
    int m0;
    if ((int)blockIdx.y < Mb1) {
        Bhi = Bhi1; Blo = Blo1; C = C1; att = att1; es_out = es1;
        m0 = blockIdx.y * 64;
    } else {
        Bhi = Bhi2; Blo = Blo2; C = C2; att = att2; es_out = es2;
        m0 = (blockIdx.y - Mb1) * 64;
    }
    const int tid = threadIdx.x;
    const int wave = tid >> 6, lane = tid & 63;
    const int quad = lane >> 4, l15 = lane & 15;
    const int n0 = blockIdx.x * 256;
    const int arow = tid >> 2, acol = (tid & 3) * 8;
    const float* ap = A + (size_t)(m0 + arow) * K + acol;
    f32x4 acc[4][4] = {};

    // ---- prologue: A(0) -> As[0]; prefetch A(32) -> va0, A(64) -> va1 ----
    {
        float4 t0 = *(const float4*)ap;
        float4 t1 = *(const float4*)(ap + 4);
        splitStore8(t0, t1, &As[0][0][arow][acol], &As[0][1][arow][acol]);
    }
    float4 va0a = *(const float4*)(ap + 32);
    float4 va0b = *(const float4*)(ap + 36);
    float4 va1a = {}, va1b = {};
    if (64 < K) { va1a = *(const float4*)(ap + 64); va1b = *(const float4*)(ap + 68); }
    __syncthreads();

    for (int k0 = 0; k0 < K; k0 += 64) {
        // ======== step 0: buffer 0, k = k0 ========
        {
            short8 bh[4], bl[4];
#pragma unroll
            for (int nt = 0; nt < 4; nt++) {
                size_t boff = (size_t)(n0 + wave * 64 + nt * 16 + l15) * K + k0 + quad * 8;
                bh[nt] = *(const short8*)&Bhi[boff];
                bl[nt] = *(const short8*)&Blo[boff];
            }
#pragma unroll
            for (int mt = 0; mt < 4; mt++) {
                short8 ah = *(const short8*)&As[0][0][mt * 16 + l15][quad * 8];
                short8 al = *(const short8*)&As[0][1][mt * 16 + l15][quad * 8];
#pragma unroll
                for (int nt = 0; nt < 4; nt++) {
                    acc[mt][nt] = __builtin_amdgcn_mfma_f32_16x16x32_bf16(ah, bh[nt], acc[mt][nt], 0, 0, 0);
                    acc[mt][nt] = __builtin_amdgcn_mfma_f32_16x16x32_bf16(ah, bl[nt], acc[mt][nt], 0, 0, 0);
                    acc[mt][nt] = __builtin_amdgcn_mfma_f32_16x16x32_bf16(al, bh[nt], acc[mt][nt], 0, 0, 0);
                }
            }
            // consume va0 = A(k0+32) -> As[1]; reissue va0 <- A(k0+96)
            splitStore8(va0a, va0b, &As[1][0][arow][acol], &As[1][1][arow][acol]);
            if (k0 + 96 < K) {
                va0a = *(const float4*)(ap + k0 + 96);
                va0b = *(const float4*)(ap + k0 + 100);
            }
        }
        __syncthreads();
        // ======== step 1: buffer 1, k = k0+32 ========
        {
            const int k1 = k0 + 32;
            short8 bh[4], bl[4];
#pragma unroll
            for (int nt = 0; nt < 4; nt++) {
                size_t boff = (size_t)(n0 + wave * 64 + nt * 16 + l15) * K + k1 + quad * 8;
                bh[nt] = *(const short8*)&Bhi[boff];
                bl[nt] = *(const short8*)&Blo[boff];
            }
#pragma unroll
            for (int mt = 0; mt < 4; mt++) {
                short8 ah = *(const short8*)&As[1][0][mt * 16 + l15][quad * 8];
                short8 al = *(const short8*)&As[1][1][mt * 16 + l15][quad * 8];
#pragma unroll
                for (int nt = 0; nt < 4; nt++) {
                    acc[mt][nt] = __builtin_amdgcn_mfma_f32_16x16x32_bf16(ah, bh[nt], acc[mt][nt], 0, 0, 0);
                    acc[mt][nt] = __builtin_amdgcn_mfma_f32_16x16x32_bf16(ah, bl[nt], acc[mt][nt], 0, 0, 0);
                    acc[mt][nt] = __builtin_amdgcn_mfma_f32_16x16x32_bf16(al, bh[nt], acc[mt][nt], 0, 0, 0);
                }
            }
            if (k0 + 64 < K) {
                // consume va1 = A(k0+64) -> As[0]; reissue va1 <- A(k0+128)
                splitStore8(va1a, va1b, &As[0][0][arow][acol], &As[0][1][arow][acol]);
                if (k0 + 128 < K) {
                    va1a = *(const float4*)(ap + k0 + 128);
                    va1b = *(const float4*)(ap + k0 + 132);
                }
            }
        }
        __syncthreads();
    }

#pragma unroll
    for (int mt = 0; mt < 4; mt++)
#pragma unroll
        for (int nt = 0; nt < 4; nt++)
#pragma unroll
            for (int r = 0; r < 4; r++) {
                int row = m0 + mt * 16 + quad * 4 + r;
                int col = n0 + wave * 64 + nt * 16 + l15;
                C[(size_t)row * N + col] = f2bfu(acc[mt][nt][r]);
            }
    // fused escore (each wave owns one head's 64 cols)
    {
        const int head = (n0 >> 6) + wave;
        float av[4];
#pragma unroll
        for (int nt = 0; nt < 4; nt++) av[nt] = att[head * 64 + nt * 16 + l15];
#pragma unroll
        for (int mt = 0; mt < 4; mt++)
#pragma unroll
            for (int r = 0; r < 4; r++) {
                float p = acc[mt][0][r] * av[0] + acc[mt][1][r] * av[1]
                        + acc[mt][2][r] * av[2] + acc[mt][3][r] * av[3];
#pragma unroll
                for (int off = 1; off < 16; off <<= 1) p += __shfl_xor(p, off);
                if (l15 == 0)
                    es_out[(size_t)(m0 + mt * 16 + quad * 4 + r) * H + head] = p;
            }
    }
}

// ---------- small MFMA GEMM (64x64 tile, Bt3 layout, fp32 A in-kernel split) — flat only ----------
__global__ __launch_bounds__(256)
void gemm_mfma(const float* __restrict__ A, const unsigned short* __restrict__ Bt3,
               float* __restrict__ C, int M, int N, int K) {
    const int KK = 3 * K;
    __shared__ unsigned short As[2][64][72];
    __shared__ unsigned short Bs[64][72];
    const int tid = threadIdx.x;
    const int wave = tid >> 6, lane = tid & 63;
    const int wr = wave >> 1, wc = wave & 1;
    const int quad = lane >> 4, l15 = lane & 15;
    const int m0 = blockIdx.y * 64, n0 = blockIdx.x * 64;
    f32x4 acc[2][2] = {};
    for (int k0 = 0; k0 < KK; k0 += 64) {
        const int seg = k0 / K;
        const int ks = k0 - seg * K;
#pragma unroll
        for (int i = 0; i < 2; i++) {
            int idx = tid + i * 256;
            int r = idx >> 3, cv = (idx & 7) * 8;
            const float* ap = &A[(size_t)(m0 + r) * K + ks + cv];
            splitStore8(*(const float4*)ap, *(const float4*)(ap + 4),
                        &As[0][r][cv], &As[1][r][cv]);
            *(short8*)&Bs[r][cv] = *(const short8*)&Bt3[(size_t)(n0 + r) * KK + k0 + cv];
        }
        __syncthreads();
        const int abank = (seg < 2) ? 0 : 1;
#pragma unroll
        for (int kk = 0; kk < 64; kk += 32) {
            short8 a[2], b[2];
#pragma unroll
            for (int t = 0; t < 2; t++) {
                a[t] = *(const short8*)&As[abank][wr * 32 + t * 16 + l15][kk + quad * 8];
                b[t] = *(const short8*)&Bs[wc * 32 + t * 16 + l15][kk + quad * 8];
            }
#pragma unroll
            for (int mt = 0; mt < 2; mt++)
#pragma unroll
                for (int nt = 0; nt < 2; nt++)
                    acc[mt][nt] = __builtin_amdgcn_mfma_f32_16x16x32_bf16(
                        a[mt], b[nt], acc[mt][nt], 0, 0, 0);
        }
        __syncthreads();
    }
#pragma unroll
    for (int mt = 0; mt < 2; mt++)
#pragma unroll
        for (int nt = 0; nt < 2; nt++)
#pragma unroll
            for (int r = 0; r < 4; r++) {
                int row = m0 + wr * 32 + mt * 16 + quad * 4 + r;
                int col = n0 + wc * 32 + nt * 16 + l15;
                C[(size_t)row * N + col] = acc[mt][nt][r];
            }
}

// ---------- GAT aggregate: one WAVE per dst node, all heads; coalesced row gathers ----------
template <int H, bool ELU>
__global__ __launch_bounds__(256)
void gat_agg2(const int* __restrict__ csr, const int* __restrict__ rs,
              const unsigned short* __restrict__ hs,  // [Ns, H*64] bf16
              const float* __restrict__ es,           // [Ns, H]
              const float* __restrict__ ed,           // [Nd, H]
              const float* __restrict__ bias,         // [H*64] or null
              float* __restrict__ out,                // [Nd, H*64] fp32
              int Nd) {
    constexpr int LH = (H == 8) ? 3 : 2;
    constexpr int EPC = 64 >> LH;
    const int lane = threadIdx.x & 63;
    const int d = blockIdx.x * (blockDim.x >> 6) + (threadIdx.x >> 6);
    if (d >= Nd) return;
    const int beg = rs[d];
    const int deg = rs[d + 1] - beg;
    const int n = deg + 1;
    const int h = lane & (H - 1);
    const int e0 = lane >> LH;
    const float edh = ed[(size_t)d * H + h];
    float mx = -1e30f;
    for (int j0 = 0; j0 < n; j0 += EPC) {
        int j = j0 + e0;
        if (j < n) {
            int s = (j < deg) ? csr[beg + j] : d;
            float a = es[(size_t)s * H + h] + edh;
            a = (a > 0.0f) ? a : 0.2f * a;
            mx = fmaxf(mx, a);
        }
    }
#pragma unroll
    for (int off = H; off < 64; off <<= 1) mx = fmaxf(mx, __shfl_xor(mx, off));
    float den = 0.0f;
    for (int j0 = 0; j0 < n; j0 += EPC) {
        int j = j0 + e0;
        if (j < n) {
            int s = (j < deg) ? csr[beg + j] : d;
            float a = es[(size_t)s * H + h] + edh;
            a = (a > 0.0f) ? a : 0.2f * a;
            den += expf(a - mx);
        }
    }
#pragma unroll
    for (int off = H; off < 64; off <<= 1) den += __shfl_xor(den, off);
    const float inv = 1.0f / den;
    const int hB = lane >> (6 - LH);
    const float mB = __shfl(mx, hB);
    const float invB = __shfl(inv, hB);
    const float edhB = __shfl(edh, hB);
    using V = typename VecT<H>::T;
    float acc[H] = {};
    const size_t rowoff = (size_t)lane * H;
    int j = 0;
    for (; j + 4 <= n; j += 4) {
        int s[4]; V rv[4]; float w[4];
#pragma unroll
        for (int u = 0; u < 4; u++) { int jj = j + u; s[u] = (jj < deg) ? csr[beg + jj] : d; }
#pragma unroll
        for (int u = 0; u < 4; u++) rv[u] = *(const V*)&hs[(size_t)s[u] * (H * 64) + rowoff];
#pragma unroll
        for (int u = 0; u < 4; u++) {
            float a = es[(size_t)s[u] * H + hB] + edhB;
            a = (a > 0.0f) ? a : 0.2f * a;
            w[u] = expf(a - mB) * invB;
        }
#pragma unroll
        for (int u = 0; u < 4; u++)
#pragma unroll
            for (int k = 0; k < H; k++) acc[k] += w[u] * bfu2f((unsigned short)rv[u][k]);
    }
    for (; j < n; j++) {
        int s = (j < deg) ? csr[beg + j] : d;
        V rv = *(const V*)&hs[(size_t)s * (H * 64) + rowoff];
        float a = es[(size_t)s * H + hB] + edhB;
        a = (a > 0.0f) ? a : 0.2f * a;
        float w = expf(a - mB) * invB;
#pragma unroll
        for (int k = 0; k < H; k++) acc[k] += w * bfu2f((unsigned short)rv[k]);
    }
#pragma unroll
    for (int k = 0; k < H; k++) {
        float v = acc[k];
        if (ELU) {
            v += bias[lane * H + k];
            v = (v > 0.0f) ? v : expm1f(v);
        }
        acc[k] = v;
    }
    float* op = out + (size_t)d * (H * 64) + rowoff;
#pragma unroll
    for (int q = 0; q < H / 4; q++)
        *(float4*)&op[q * 4] = *(float4*)&acc[q * 4];
}

// ---------- final ----------
__global__ void final_kernel(const float* __restrict__ acc2, const float* __restrict__ bias2,
                             const float* __restrict__ fbuf, const float* __restrict__ flat_b,
                             const float* __restrict__ last, const float* __restrict__ outW,
                             const float* __restrict__ outb, float* __restrict__ out, int N) {
    int n = blockIdx.x * blockDim.x + threadIdx.x;
    if (n >= N) return;
    float s = outb[0];
    const float* a = acc2 + (size_t)n * 256;
    for (int c = 0; c < 64; c++) {
        float h2 = 0.25f * (a[c] + a[64 + c] + a[128 + c] + a[192 + c]) + bias2[c];
        s += h2 * outW[c];
        s += (fbuf[(size_t)n * 64 + c] + flat_b[c]) * outW[64 + c];
        s += last[(size_t)n * 64 + c] * outW[128 + c];
    }
    out[n] = s;
}

extern "C" void kernel_launch(void* const* d_in, const int* in_sizes, int n_in,
                              void* d_out, int out_size, void* d_ws, size_t ws_size,
                              hipStream_t stream) {
    const float* x    = (const float*)d_in[0];
    const float* flat = (const float*)d_in[1];
    const float* last = (const float*)d_in[2];
    const int*  es1i  = (const int*)d_in[3];
    const int*  ed1i  = (const int*)d_in[4];
    const int*  es2i  = (const int*)d_in[5];
    const int*  ed2i  = (const int*)d_in[6];
    const float* W1s  = (const float*)d_in[7];
    const float* W1d  = (const float*)d_in[8];
    const float* a1s  = (const float*)d_in[9];
    const float* a1d  = (const float*)d_in[10];
    const float* b1   = (const float*)d_in[11];
    const float* W2s  = (const float*)d_in[12];
    const float* W2d  = (const float*)d_in[13];
    const float* a2s  = (const float*)d_in[14];
    const float* a2d  = (const float*)d_in[15];
    const float* b2   = (const float*)d_in[16];
    const float* fW   = (const float*)d_in[17];
    const float* fb   = (const float*)d_in[18];
    const float* oW   = (const float*)d_in[19];
    const float* ob   = (const float*)d_in[20];
    float* out = (float*)d_out;

    float* ws = (float*)d_ws;
    // ---- layout (float-element offsets; proven footprint) ----
    unsigned short* hs1_bf = (unsigned short*)ws;                  // 40,960,000 us
    unsigned short* hd1_bf = (unsigned short*)(ws + 20480000);     //  8,192,000 us
    float* es1f = ws + 24576000;                                   // 640,000
    float* ed1f = ws + 25216000;                                   // 128,000
    float* acc1 = ws + 25344000;                                   // 8,192,000 -> 33,536,000
    unsigned short* wb = (unsigned short*)(ws + 54016000);
    unsigned short* w1s_hi = wb;
    unsigned short* w1s_lo = wb + 131072;
    unsigned short* w1d_hi = wb + 262144;
    unsigned short* w1d_lo = wb + 393216;
    unsigned short* w2s_hi = wb + 524288;
    unsigned short* w2s_lo = wb + 655360;
    unsigned short* w2d_hi = wb + 786432;
    unsigned short* w2d_lo = wb + 917504;
    unsigned short* fw_t3  = wb + 1048576;
    int* ibase   = (int*)(ws + 54816000);
    int* cnt1    = ibase;
    int* cursor1 = ibase + 16000;
    int* cnt2    = ibase + 32000;
    int* cursor2 = ibase + 36096;
    int* start1  = ibase + 40192;
    int* start2  = ibase + 56193;
    int* csr1    = ibase + 60290;
    int* csr2    = ibase + 316290;
    const size_t NEED = ((size_t)54816000 + 381826) * 4;
    if (ws_size < NEED) {
        fprintf(stderr, "kernel_launch: ws_size %zu < needed %zu\n", ws_size, NEED);
        return;
    }
    unsigned short* hs2_bf = (unsigned short*)ws;
    unsigned short* hd2_bf = (unsigned short*)(ws + 2048000);
    float* es2f = ws + 2572288;
    float* ed2f = ws + 2636288;
    float* acc2 = ws + 2652672;
    float* fbuf = ws + 3701248;

    // ---- prep (1 launch) + CSR build (3 launches) ----
    {
        int total = 262144 + 262144 + 8192 + 40192;
        prep_kernel<<<(total + 255) / 256, 256, 0, stream>>>(
            W1s, W1d, w1s_hi, w1s_lo, w1d_hi, w1d_lo,
            W2s, W2d, w2s_hi, w2s_lo, w2d_hi, w2d_lo,
            fW, fw_t3, ibase, 40192);
    }
    hist_dual<<<(E1 + E2 + 255) / 256, 256, 0, stream>>>(ed1i, cnt1, ed2i, cnt2);
    scan_dual<<<2, 1024, 0, stream>>>(cnt1, start1, N2, cnt2, start2, N3);
    fill_dual<<<(E1 + E2 + 255) / 256, 256, 0, stream>>>(
        es1i, ed1i, start1, cursor1, csr1, es2i, ed2i, start2, cursor2, csr2);

    // ---- layer 1: src+dst GEMMs in one grid, fused escore ----
    gemm_fused<<<dim3(2, N1 / 64 + N2 / 64), 256, 0, stream>>>(
        x, w1s_hi, w1s_lo, hs1_bf, a1s, es1f,
        w1d_hi, w1d_lo, hd1_bf, a1d, ed1f,
        N1 / 64, 512, 256, 8);
    gat_agg2<8, true><<<N2 / 4, 256, 0, stream>>>(csr1, start1, hs1_bf, es1f, ed1f, b1, acc1, N2);

    // ---- layer 2: src+dst GEMMs in one grid ----
    gemm_fused<<<dim3(1, N2 / 64 + N3 / 64), 256, 0, stream>>>(
        acc1, w2s_hi, w2s_lo, hs2_bf, a2s, es2f,
        w2d_hi, w2d_lo, hd2_bf, a2d, ed2f,
        N2 / 64, 256, 512, 4);
    gat_agg2<4, false><<<N3 / 4, 256, 0, stream>>>(csr2, start2, hs2_bf, es2f, ed2f, nullptr, acc2, N3);

    // ---- flat MLP + output ----
    gemm_mfma<<<dim3(1, N3 / 64), 256, 0, stream>>>(flat, fw_t3, fbuf, N3, 64, 128);
    final_kernel<<<(N3 + 255) / 256, 256, 0, stream>>>(acc2, b2, fbuf, fb, last, oW, ob, out, N3);
}